// Round 3
// baseline (875.268 us; speedup 1.0000x reference)
//
#include <hip/hip_runtime.h>

#define B_TREES 128
#define NPT 255
#define NTOT (B_TREES * NPT)   // 32640
#define FIN 64
#define HH 256

__device__ __forceinline__ float sigf(float x) {
    return __frcp_rn(1.0f + __expf(-x));
}
__device__ __forceinline__ float tanh_fast(float x) {
    return __builtin_fmaf(2.0f, sigf(2.0f * x), -1.0f);
}

// ---------------------------------------------------------------------------
// Transpose weights into K-major layout so lanes read consecutive addresses.
// WT[k][j], k<256, j<1024: j<768 -> Uiou[j][k], else Uf[j-768][k]
// WxT[k][j], k<64,  j<1024: j<768 -> Wiou[j][k], else 2*Wf[j-768][k]  (x2 fold)
// ---------------------------------------------------------------------------
__global__ __launch_bounds__(256) void transpose_weights(
    const float* __restrict__ Uiou, const float* __restrict__ Uf,
    const float* __restrict__ Wiou, const float* __restrict__ Wf,
    float* __restrict__ WT, float* __restrict__ WxT)
{
    int idx = blockIdx.x * 256 + threadIdx.x;
    if (idx < 256 * 1024) {
        int k = idx >> 10, j = idx & 1023;
        WT[idx] = (j < 768) ? Uiou[(size_t)j * 256 + k] : Uf[(size_t)(j - 768) * 256 + k];
    } else {
        int idx2 = idx - 256 * 1024;   // < 64*1024 by grid construction
        int k = idx2 >> 10, j = idx2 & 1023;
        WxT[idx2] = (j < 768) ? Wiou[(size_t)j * 64 + k] : 2.0f * Wf[(size_t)(j - 768) * 64 + k];
    }
}

// ---------------------------------------------------------------------------
// Shared dot-loop for the 256-thread internal kernels: accumulates NB nodes.
// ---------------------------------------------------------------------------
template<int NB, bool TR>
__device__ __forceinline__ void dot_loops(
    int tid,
    const float* __restrict__ WT, const float* __restrict__ WxT,
    const float* __restrict__ Uiou, const float* __restrict__ Uf,
    const float* __restrict__ Wiou, const float* __restrict__ Wf,
    const float (*hs)[HH], const float (*hd)[HH], const float (*xs)[FIN],
    float* ai, float* ao, float* au, float* fs, float* fd)
{
    // ---- U part, K = 256 ----
    for (int k4 = 0; k4 < 64; ++k4) {
        float wi[4], wo[4], wu[4], wf[4];
        if constexpr (TR) {
#pragma unroll
            for (int q = 0; q < 4; ++q) {
                int kk = (4 * k4 + q) * 1024 + tid;
                wi[q] = WT[kk];
                wo[q] = WT[kk + 256];
                wu[q] = WT[kk + 512];
                wf[q] = WT[kk + 768];
            }
        } else {
            float4 t0 = *(const float4*)(Uiou + (size_t)tid * HH + 4 * k4);
            float4 t1 = *(const float4*)(Uiou + (size_t)(tid + 256) * HH + 4 * k4);
            float4 t2 = *(const float4*)(Uiou + (size_t)(tid + 512) * HH + 4 * k4);
            float4 t3 = *(const float4*)(Uf + (size_t)tid * HH + 4 * k4);
            wi[0] = t0.x; wi[1] = t0.y; wi[2] = t0.z; wi[3] = t0.w;
            wo[0] = t1.x; wo[1] = t1.y; wo[2] = t1.z; wo[3] = t1.w;
            wu[0] = t2.x; wu[1] = t2.y; wu[2] = t2.z; wu[3] = t2.w;
            wf[0] = t3.x; wf[1] = t3.y; wf[2] = t3.z; wf[3] = t3.w;
        }
#pragma unroll
        for (int n = 0; n < NB; ++n) {
            float4 s4 = ((const float4*)hs[n])[k4];
            float4 d4 = ((const float4*)hd[n])[k4];
            ai[n] += wi[0] * s4.x + wi[1] * s4.y + wi[2] * s4.z + wi[3] * s4.w;
            ao[n] += wo[0] * s4.x + wo[1] * s4.y + wo[2] * s4.z + wo[3] * s4.w;
            au[n] += wu[0] * s4.x + wu[1] * s4.y + wu[2] * s4.z + wu[3] * s4.w;
            fs[n] += wf[0] * s4.x + wf[1] * s4.y + wf[2] * s4.z + wf[3] * s4.w;
            fd[n] += wf[0] * d4.x + wf[1] * d4.y + wf[2] * d4.z + wf[3] * d4.w;
        }
    }
    // ---- W part, K = 64 ----
    for (int k4 = 0; k4 < 16; ++k4) {
        float wi[4], wo[4], wu[4], wf[4];
        if constexpr (TR) {
#pragma unroll
            for (int q = 0; q < 4; ++q) {
                int kk = (4 * k4 + q) * 1024 + tid;
                wi[q] = WxT[kk];
                wo[q] = WxT[kk + 256];
                wu[q] = WxT[kk + 512];
                wf[q] = WxT[kk + 768];
            }
        } else {
            float4 t0 = *(const float4*)(Wiou + (size_t)tid * FIN + 4 * k4);
            float4 t1 = *(const float4*)(Wiou + (size_t)(tid + 256) * FIN + 4 * k4);
            float4 t2 = *(const float4*)(Wiou + (size_t)(tid + 512) * FIN + 4 * k4);
            float4 t3 = *(const float4*)(Wf + (size_t)tid * FIN + 4 * k4);
            wi[0] = t0.x; wi[1] = t0.y; wi[2] = t0.z; wi[3] = t0.w;
            wo[0] = t1.x; wo[1] = t1.y; wo[2] = t1.z; wo[3] = t1.w;
            wu[0] = t2.x; wu[1] = t2.y; wu[2] = t2.z; wu[3] = t2.w;
            wf[0] = 2.0f * t3.x; wf[1] = 2.0f * t3.y; wf[2] = 2.0f * t3.z; wf[3] = 2.0f * t3.w;
        }
#pragma unroll
        for (int n = 0; n < NB; ++n) {
            float4 x4 = ((const float4*)xs[n])[k4];
            ai[n] += wi[0] * x4.x + wi[1] * x4.y + wi[2] * x4.z + wi[3] * x4.w;
            ao[n] += wo[0] * x4.x + wo[1] * x4.y + wo[2] * x4.z + wo[3] * x4.w;
            au[n] += wu[0] * x4.x + wu[1] * x4.y + wu[2] * x4.z + wu[3] * x4.w;
            fs[n] += wf[0] * x4.x + wf[1] * x4.y + wf[2] * x4.z + wf[3] * x4.w;
        }
    }
}

// ---------------------------------------------------------------------------
// Leaves: iou = W_iou x + b; c = sig(i)*tanh(u); h = sig(o)*tanh(c).
// 16 leaves / block, 1024 blocks.
// ---------------------------------------------------------------------------
template<bool TR>
__global__ __launch_bounds__(256) void leaf_v2(
    const float* __restrict__ feat,
    const float* __restrict__ WxT, const float* __restrict__ Wiou,
    const float* __restrict__ biou,
    float* __restrict__ h, float* __restrict__ c)
{
    const int NB = 16;
    __shared__ float xs[NB][FIN];
    int tid = threadIdx.x;
    int l0 = blockIdx.x * NB;
    int b = l0 >> 7;
    int g0 = b * NPT + 127 + (l0 & 127);
    const float* fb = feat + (size_t)g0 * FIN;
    for (int i = tid; i < NB * FIN; i += 256) ((float*)xs)[i] = fb[i];
    __syncthreads();

    float ai[NB], ao[NB], au[NB];
#pragma unroll
    for (int n = 0; n < NB; ++n) { ai[n] = 0.f; ao[n] = 0.f; au[n] = 0.f; }

    for (int k4 = 0; k4 < 16; ++k4) {
        float wi[4], wo[4], wu[4];
        if constexpr (TR) {
#pragma unroll
            for (int q = 0; q < 4; ++q) {
                int kk = (4 * k4 + q) * 1024 + tid;
                wi[q] = WxT[kk]; wo[q] = WxT[kk + 256]; wu[q] = WxT[kk + 512];
            }
        } else {
            float4 t0 = *(const float4*)(Wiou + (size_t)tid * FIN + 4 * k4);
            float4 t1 = *(const float4*)(Wiou + (size_t)(tid + 256) * FIN + 4 * k4);
            float4 t2 = *(const float4*)(Wiou + (size_t)(tid + 512) * FIN + 4 * k4);
            wi[0] = t0.x; wi[1] = t0.y; wi[2] = t0.z; wi[3] = t0.w;
            wo[0] = t1.x; wo[1] = t1.y; wo[2] = t1.z; wo[3] = t1.w;
            wu[0] = t2.x; wu[1] = t2.y; wu[2] = t2.z; wu[3] = t2.w;
        }
#pragma unroll
        for (int n = 0; n < NB; ++n) {
            float4 x4 = ((const float4*)xs[n])[k4];
            ai[n] += wi[0] * x4.x + wi[1] * x4.y + wi[2] * x4.z + wi[3] * x4.w;
            ao[n] += wo[0] * x4.x + wo[1] * x4.y + wo[2] * x4.z + wo[3] * x4.w;
            au[n] += wu[0] * x4.x + wu[1] * x4.y + wu[2] * x4.z + wu[3] * x4.w;
        }
    }

    float bi = biou[tid], bo = biou[tid + 256], bu = biou[tid + 512];
#pragma unroll
    for (int n = 0; n < NB; ++n) {
        float iv = sigf(ai[n] + bi);
        float ov = sigf(ao[n] + bo);
        float uv = tanh_fast(au[n] + bu);
        float cv = iv * uv;
        float hv = ov * tanh_fast(cv);
        c[(size_t)(g0 + n) * HH + tid] = cv;
        h[(size_t)(g0 + n) * HH + tid] = hv;
    }
}

// ---------------------------------------------------------------------------
// Internal levels t=1 (NB=16) and t=2 (NB=8).
// hs = h_c1 + h_c2, hd = h_c1 - h_c2; U_f h_ck = (fs +- fd)/2, with 2*W_f x
// folded into fs.
// ---------------------------------------------------------------------------
template<int NB, bool TR>
__global__ __launch_bounds__(256, 2) void internal_v2(
    const float* __restrict__ feat,
    const float* __restrict__ WT, const float* __restrict__ WxT,
    const float* __restrict__ Uiou, const float* __restrict__ Uf,
    const float* __restrict__ Wiou, const float* __restrict__ Wf,
    const float* __restrict__ biou, const float* __restrict__ bfv,
    float* __restrict__ h, float* __restrict__ c,
    int Lt, int lg)
{
    __shared__ float hs[NB][HH], hd[NB][HH];
    __shared__ float xs[NB][FIN];
    int tid = threadIdx.x;
    int m0 = blockIdx.x * NB;
    int b = m0 >> lg;
    int ii0 = Lt + (m0 & ((1 << lg) - 1));
    int g0 = b * NPT + ii0;
    int gc0 = g0 + ii0 + 1;              // = b*NPT + 2*ii0 + 1

#pragma unroll
    for (int j = 0; j < NB; ++j) {
        float a  = h[(size_t)(gc0 + 2 * j) * HH + tid];
        float bb = h[(size_t)(gc0 + 2 * j + 1) * HH + tid];
        hs[j][tid] = a + bb;
        hd[j][tid] = a - bb;
    }
    const float* fb = feat + (size_t)g0 * FIN;
    for (int i = tid; i < NB * FIN; i += 256) ((float*)xs)[i] = fb[i];
    __syncthreads();

    float ai[NB], ao[NB], au[NB], fs[NB], fd[NB];
#pragma unroll
    for (int n = 0; n < NB; ++n) { ai[n] = 0.f; ao[n] = 0.f; au[n] = 0.f; fs[n] = 0.f; fd[n] = 0.f; }

    dot_loops<NB, TR>(tid, WT, WxT, Uiou, Uf, Wiou, Wf, hs, hd, xs, ai, ao, au, fs, fd);

    float bi = biou[tid], bo = biou[tid + 256], bu = biou[tid + 512], bF = bfv[tid];
#pragma unroll
    for (int n = 0; n < NB; ++n) {
        float iv = sigf(ai[n] + bi);
        float ov = sigf(ao[n] + bo);
        float uv = tanh_fast(au[n] + bu);
        float f1 = sigf(0.5f * (fs[n] + fd[n]) + bF);
        float f2 = sigf(0.5f * (fs[n] - fd[n]) + bF);
        float c1 = c[(size_t)(gc0 + 2 * n) * HH + tid];
        float c2 = c[(size_t)(gc0 + 2 * n + 1) * HH + tid];
        float cv = iv * uv + f1 * c1 + f2 * c2;
        float hv = ov * tanh_fast(cv);
        c[(size_t)(g0 + n) * HH + tid] = cv;
        h[(size_t)(g0 + n) * HH + tid] = hv;
    }
}

// ---------------------------------------------------------------------------
// Merged tail, WIDE: one 1024-thread block per tree, levels nt=16,8,4,2,1.
// Thread (g = tid>>8, j = tid&255) owns output columns {j, j+256, j+512, j+768}
// for the level's node subset n == g (mod 4). 16 waves/CU for latency hiding
// (vs 4 in the old 256-thread tail: VALUBusy was 17%, pure latency-bound).
// ---------------------------------------------------------------------------
template<int NT, bool FIRST, bool TR>
__device__ void tw_level(
    int gb, const float* __restrict__ feat,
    const float* __restrict__ WT, const float* __restrict__ WxT,
    const float* __restrict__ Uiou, const float* __restrict__ Uf,
    const float* __restrict__ Wiou, const float* __restrict__ Wf,
    const float* __restrict__ biou, const float* __restrict__ bfv,
    float* __restrict__ h, float* __restrict__ c,
    float (*hl)[HH], float (*cl)[HH],
    float (*hs)[HH], float (*hd)[HH], float (*xs)[FIN])
{
    const int tid = threadIdx.x;
    const int j = tid & 255;
    const int g = tid >> 8;
    const int first = NT - 1;
    constexpr int NN = (NT >= 4) ? NT / 4 : 1;
    const bool act = (NT >= 4) || (g < NT);

    // build hs/hd (+stage x)
    if constexpr (FIRST) {
        for (int i = tid; i < NT * HH; i += 1024) {
            int n = i >> 8, k = i & 255;
            int ch = 2 * (first + n) + 1;
            float a  = h[(size_t)(gb + ch) * HH + k];
            float bb = h[(size_t)(gb + ch + 1) * HH + k];
            hs[n][k] = a + bb;
            hd[n][k] = a - bb;
        }
    } else {
        for (int i = tid; i < NT * HH; i += 1024) {
            int n = i >> 8, k = i & 255;
            int ch = 2 * (first + n) + 1;
            float a = hl[ch][k], bb = hl[ch + 1][k];
            hs[n][k] = a + bb;
            hd[n][k] = a - bb;
        }
    }
    for (int i = tid; i < NT * FIN; i += 1024)
        ((float*)xs)[i] = feat[(size_t)(gb + first) * FIN + i];
    __syncthreads();

    float ai[NN], ao[NN], au[NN], fs[NN], fd[NN];
#pragma unroll
    for (int q = 0; q < NN; ++q) { ai[q] = 0.f; ao[q] = 0.f; au[q] = 0.f; fs[q] = 0.f; fd[q] = 0.f; }

    if (act) {
        // ---- U part, K = 256 ----
        for (int k4 = 0; k4 < 64; ++k4) {
            float wi[4], wo[4], wu[4], wf[4];
            if constexpr (TR) {
#pragma unroll
                for (int q = 0; q < 4; ++q) {
                    int kk = (4 * k4 + q) * 1024 + j;
                    wi[q] = WT[kk];
                    wo[q] = WT[kk + 256];
                    wu[q] = WT[kk + 512];
                    wf[q] = WT[kk + 768];
                }
            } else {
                float4 t0 = *(const float4*)(Uiou + (size_t)j * HH + 4 * k4);
                float4 t1 = *(const float4*)(Uiou + (size_t)(j + 256) * HH + 4 * k4);
                float4 t2 = *(const float4*)(Uiou + (size_t)(j + 512) * HH + 4 * k4);
                float4 t3 = *(const float4*)(Uf + (size_t)j * HH + 4 * k4);
                wi[0] = t0.x; wi[1] = t0.y; wi[2] = t0.z; wi[3] = t0.w;
                wo[0] = t1.x; wo[1] = t1.y; wo[2] = t1.z; wo[3] = t1.w;
                wu[0] = t2.x; wu[1] = t2.y; wu[2] = t2.z; wu[3] = t2.w;
                wf[0] = t3.x; wf[1] = t3.y; wf[2] = t3.z; wf[3] = t3.w;
            }
#pragma unroll
            for (int q = 0; q < NN; ++q) {
                int n = (NT >= 4) ? (g + 4 * q) : g;
                float4 s4 = ((const float4*)hs[n])[k4];
                float4 d4 = ((const float4*)hd[n])[k4];
                ai[q] += wi[0] * s4.x + wi[1] * s4.y + wi[2] * s4.z + wi[3] * s4.w;
                ao[q] += wo[0] * s4.x + wo[1] * s4.y + wo[2] * s4.z + wo[3] * s4.w;
                au[q] += wu[0] * s4.x + wu[1] * s4.y + wu[2] * s4.z + wu[3] * s4.w;
                fs[q] += wf[0] * s4.x + wf[1] * s4.y + wf[2] * s4.z + wf[3] * s4.w;
                fd[q] += wf[0] * d4.x + wf[1] * d4.y + wf[2] * d4.z + wf[3] * d4.w;
            }
        }
        // ---- W part, K = 64 ----
        for (int k4 = 0; k4 < 16; ++k4) {
            float wi[4], wo[4], wu[4], wf[4];
            if constexpr (TR) {
#pragma unroll
                for (int q = 0; q < 4; ++q) {
                    int kk = (4 * k4 + q) * 1024 + j;
                    wi[q] = WxT[kk];
                    wo[q] = WxT[kk + 256];
                    wu[q] = WxT[kk + 512];
                    wf[q] = WxT[kk + 768];
                }
            } else {
                float4 t0 = *(const float4*)(Wiou + (size_t)j * FIN + 4 * k4);
                float4 t1 = *(const float4*)(Wiou + (size_t)(j + 256) * FIN + 4 * k4);
                float4 t2 = *(const float4*)(Wiou + (size_t)(j + 512) * FIN + 4 * k4);
                float4 t3 = *(const float4*)(Wf + (size_t)j * FIN + 4 * k4);
                wi[0] = t0.x; wi[1] = t0.y; wi[2] = t0.z; wi[3] = t0.w;
                wo[0] = t1.x; wo[1] = t1.y; wo[2] = t1.z; wo[3] = t1.w;
                wu[0] = t2.x; wu[1] = t2.y; wu[2] = t2.z; wu[3] = t2.w;
                wf[0] = 2.0f * t3.x; wf[1] = 2.0f * t3.y; wf[2] = 2.0f * t3.z; wf[3] = 2.0f * t3.w;
            }
#pragma unroll
            for (int q = 0; q < NN; ++q) {
                int n = (NT >= 4) ? (g + 4 * q) : g;
                float4 x4 = ((const float4*)xs[n])[k4];
                ai[q] += wi[0] * x4.x + wi[1] * x4.y + wi[2] * x4.z + wi[3] * x4.w;
                ao[q] += wo[0] * x4.x + wo[1] * x4.y + wo[2] * x4.z + wo[3] * x4.w;
                au[q] += wu[0] * x4.x + wu[1] * x4.y + wu[2] * x4.z + wu[3] * x4.w;
                fs[q] += wf[0] * x4.x + wf[1] * x4.y + wf[2] * x4.z + wf[3] * x4.w;
            }
        }

        float bi = biou[j], bo = biou[j + 256], bu = biou[j + 512], bF = bfv[j];
#pragma unroll
        for (int q = 0; q < NN; ++q) {
            int n = (NT >= 4) ? (g + 4 * q) : g;
            int node = first + n;
            int ch = 2 * node + 1;
            float iv = sigf(ai[q] + bi);
            float ov = sigf(ao[q] + bo);
            float uv = tanh_fast(au[q] + bu);
            float f1 = sigf(0.5f * (fs[q] + fd[q]) + bF);
            float f2 = sigf(0.5f * (fs[q] - fd[q]) + bF);
            float c1, c2;
            if constexpr (FIRST) {
                c1 = c[(size_t)(gb + ch) * HH + j];
                c2 = c[(size_t)(gb + ch + 1) * HH + j];
            } else {
                c1 = cl[ch][j];
                c2 = cl[ch + 1][j];
            }
            float cv = iv * uv + f1 * c1 + f2 * c2;
            float hv = ov * tanh_fast(cv);
            hl[node][j] = hv;
            cl[node][j] = cv;
            h[(size_t)(gb + node) * HH + j] = hv;
            c[(size_t)(gb + node) * HH + j] = cv;
        }
    }
    __syncthreads();   // protect hs/hd/hl/cl before next level
}

template<bool TR>
__global__ __launch_bounds__(1024, 4) void tree_top_wide(
    const float* __restrict__ feat,
    const float* __restrict__ WT, const float* __restrict__ WxT,
    const float* __restrict__ Uiou, const float* __restrict__ Uf,
    const float* __restrict__ Wiou, const float* __restrict__ Wf,
    const float* __restrict__ biou, const float* __restrict__ bfv,
    float* __restrict__ h, float* __restrict__ c)
{
    __shared__ float hl[31][HH], cl[31][HH];
    __shared__ float hs[16][HH], hd[16][HH];
    __shared__ float xs[16][FIN];
    int gb = blockIdx.x * NPT;
    tw_level<16, true,  TR>(gb, feat, WT, WxT, Uiou, Uf, Wiou, Wf, biou, bfv, h, c, hl, cl, hs, hd, xs);
    tw_level<8,  false, TR>(gb, feat, WT, WxT, Uiou, Uf, Wiou, Wf, biou, bfv, h, c, hl, cl, hs, hd, xs);
    tw_level<4,  false, TR>(gb, feat, WT, WxT, Uiou, Uf, Wiou, Wf, biou, bfv, h, c, hl, cl, hs, hd, xs);
    tw_level<2,  false, TR>(gb, feat, WT, WxT, Uiou, Uf, Wiou, Wf, biou, bfv, h, c, hl, cl, hs, hd, xs);
    tw_level<1,  false, TR>(gb, feat, WT, WxT, Uiou, Uf, Wiou, Wf, biou, bfv, h, c, hl, cl, hs, hd, xs);
}

// ---------------------------------------------------------------------------
// Head: per tree mean over 255 h rows -> lin0 + ReLU -> lin1 dot.
// ---------------------------------------------------------------------------
__global__ __launch_bounds__(256) void head_kernel(
    const float* __restrict__ h,
    const float* __restrict__ l0w, const float* __restrict__ l0b,
    const float* __restrict__ l1w, const float* __restrict__ l1b,
    float* __restrict__ out)
{
    __shared__ float ms[HH];
    __shared__ float red[4];
    int b = blockIdx.x, tid = threadIdx.x;
    const float* hb = h + (size_t)b * NPT * HH;

    float a0 = 0.f, a1 = 0.f, a2 = 0.f, a3 = 0.f;
    int i = 0;
    for (; i + 3 < NPT; i += 4) {
        a0 += hb[(size_t)(i + 0) * HH + tid];
        a1 += hb[(size_t)(i + 1) * HH + tid];
        a2 += hb[(size_t)(i + 2) * HH + tid];
        a3 += hb[(size_t)(i + 3) * HH + tid];
    }
    for (; i < NPT; ++i) a0 += hb[(size_t)i * HH + tid];
    ms[tid] = (a0 + a1 + a2 + a3) * (1.0f / (float)NPT);
    __syncthreads();

    const float4* L0 = (const float4*)(l0w + (size_t)tid * HH);
    float y = 0.f;
    for (int k4 = 0; k4 < HH / 4; ++k4) {
        float4 w = L0[k4];
        float4 m4 = ((const float4*)ms)[k4];
        y += w.x * m4.x + w.y * m4.y + w.z * m4.z + w.w * m4.w;
    }
    y += l0b[tid];
    y = fmaxf(y, 0.f);

    float v = y * l1w[tid];
    for (int off = 32; off > 0; off >>= 1) v += __shfl_down(v, off, 64);
    if ((tid & 63) == 0) red[tid >> 6] = v;
    __syncthreads();
    if (tid == 0) out[b] = red[0] + red[1] + red[2] + red[3] + l1b[0];
}

// ---------------------------------------------------------------------------
extern "C" void kernel_launch(void* const* d_in, const int* in_sizes, int n_in,
                              void* d_out, int out_size, void* d_ws, size_t ws_size,
                              hipStream_t stream)
{
    const float* feat = (const float*)d_in[0];
    const float* Wiou = (const float*)d_in[4];
    const float* biou = (const float*)d_in[5];
    const float* Uiou = (const float*)d_in[6];
    const float* Wf   = (const float*)d_in[7];
    const float* bfv  = (const float*)d_in[8];
    const float* Uf   = (const float*)d_in[9];
    const float* l0w  = (const float*)d_in[10];
    const float* l0b  = (const float*)d_in[11];
    const float* l1w  = (const float*)d_in[12];
    const float* l1b  = (const float*)d_in[13];

    float* h  = (float*)d_ws;
    float* c  = h + (size_t)NTOT * HH;
    float* WT  = c + (size_t)NTOT * HH;
    float* WxT = WT + 256 * 1024;
    size_t need = ((size_t)NTOT * HH * 2 + 256 * 1024 + 64 * 1024) * sizeof(float);
    bool tr = (ws_size >= need);

    if (tr) {
        transpose_weights<<<1280, 256, 0, stream>>>(Uiou, Uf, Wiou, Wf, WT, WxT);
        leaf_v2<true><<<1024, 256, 0, stream>>>(feat, WxT, Wiou, biou, h, c);
        internal_v2<16, true><<<512, 256, 0, stream>>>(feat, WT, WxT, Uiou, Uf, Wiou, Wf,
                                                       biou, bfv, h, c, 63, 6);
        internal_v2<8, true><<<512, 256, 0, stream>>>(feat, WT, WxT, Uiou, Uf, Wiou, Wf,
                                                      biou, bfv, h, c, 31, 5);
        tree_top_wide<true><<<128, 1024, 0, stream>>>(feat, WT, WxT, Uiou, Uf, Wiou, Wf,
                                                      biou, bfv, h, c);
    } else {
        leaf_v2<false><<<1024, 256, 0, stream>>>(feat, WxT, Wiou, biou, h, c);
        internal_v2<16, false><<<512, 256, 0, stream>>>(feat, WT, WxT, Uiou, Uf, Wiou, Wf,
                                                        biou, bfv, h, c, 63, 6);
        internal_v2<8, false><<<512, 256, 0, stream>>>(feat, WT, WxT, Uiou, Uf, Wiou, Wf,
                                                       biou, bfv, h, c, 31, 5);
        tree_top_wide<false><<<128, 1024, 0, stream>>>(feat, WT, WxT, Uiou, Uf, Wiou, Wf,
                                                       biou, bfv, h, c);
    }
    head_kernel<<<B_TREES, 256, 0, stream>>>(h, l0w, l0b, l1w, l1b, (float*)d_out);
}

// Round 4
// 622.365 us; speedup vs baseline: 1.4064x; 1.4064x over previous
//
#include <hip/hip_runtime.h>

#define B_TREES 128
#define NPT 255
#define NTOT (B_TREES * NPT)   // 32640
#define FIN 64
#define HH 256

__device__ __forceinline__ float sigf(float x) {
    return __frcp_rn(1.0f + __expf(-x));
}
__device__ __forceinline__ float tanh_fast(float x) {
    return __builtin_fmaf(2.0f, sigf(2.0f * x), -1.0f);
}

// ---------------------------------------------------------------------------
// Transposed weight layout, float4-friendly:
// WT stores, for k4 in [0,64), col in [0,1024), q in [0,4):
//   WT[k4*4096 + col*4 + q] = M[col][4*k4+q]
// where M[col][k] = Uiou[col][k] (col<768) else Uf[col-768][k].
// So (float4*)WT + k4*1024 + col is the 4 K-values for that column: one
// global_load_dwordx4 per weight class per k4 iteration (was 4 x b32).
// WxT likewise for the K=64 W-matrices, with 2*Wf folded (x2 for the fs trick).
// ---------------------------------------------------------------------------
__global__ __launch_bounds__(256) void transpose_weights(
    const float* __restrict__ Uiou, const float* __restrict__ Uf,
    const float* __restrict__ Wiou, const float* __restrict__ Wf,
    float* __restrict__ WT, float* __restrict__ WxT)
{
    int idx = blockIdx.x * 256 + threadIdx.x;
    if (idx < 256 * 1024) {
        int k = idx >> 10, j = idx & 1023;
        float v = (j < 768) ? Uiou[(size_t)j * 256 + k] : Uf[(size_t)(j - 768) * 256 + k];
        WT[(size_t)(k >> 2) * 4096 + j * 4 + (k & 3)] = v;
    } else {
        int idx2 = idx - 256 * 1024;   // < 64*1024 by grid construction
        int k = idx2 >> 10, j = idx2 & 1023;
        float v = (j < 768) ? Wiou[(size_t)j * 64 + k] : 2.0f * Wf[(size_t)(j - 768) * 64 + k];
        WxT[(size_t)(k >> 2) * 4096 + j * 4 + (k & 3)] = v;
    }
}

// ---------------------------------------------------------------------------
// Shared dot-loop for the 256-thread internal kernels: accumulates NB nodes.
// ---------------------------------------------------------------------------
template<int NB, bool TR>
__device__ __forceinline__ void dot_loops(
    int tid,
    const float* __restrict__ WT, const float* __restrict__ WxT,
    const float* __restrict__ Uiou, const float* __restrict__ Uf,
    const float* __restrict__ Wiou, const float* __restrict__ Wf,
    const float (*hs)[HH], const float (*hd)[HH], const float (*xs)[FIN],
    float* ai, float* ao, float* au, float* fs, float* fd)
{
    const float4* WT4  = (const float4*)WT;
    const float4* WxT4 = (const float4*)WxT;
    // ---- U part, K = 256 ----
    for (int k4 = 0; k4 < 64; ++k4) {
        float4 wi, wo, wu, wf;
        if constexpr (TR) {
            size_t base = (size_t)k4 * 1024 + tid;
            wi = WT4[base];
            wo = WT4[base + 256];
            wu = WT4[base + 512];
            wf = WT4[base + 768];
        } else {
            wi = *(const float4*)(Uiou + (size_t)tid * HH + 4 * k4);
            wo = *(const float4*)(Uiou + (size_t)(tid + 256) * HH + 4 * k4);
            wu = *(const float4*)(Uiou + (size_t)(tid + 512) * HH + 4 * k4);
            wf = *(const float4*)(Uf + (size_t)tid * HH + 4 * k4);
        }
#pragma unroll
        for (int n = 0; n < NB; ++n) {
            float4 s4 = ((const float4*)hs[n])[k4];
            float4 d4 = ((const float4*)hd[n])[k4];
            ai[n] += wi.x * s4.x + wi.y * s4.y + wi.z * s4.z + wi.w * s4.w;
            ao[n] += wo.x * s4.x + wo.y * s4.y + wo.z * s4.z + wo.w * s4.w;
            au[n] += wu.x * s4.x + wu.y * s4.y + wu.z * s4.z + wu.w * s4.w;
            fs[n] += wf.x * s4.x + wf.y * s4.y + wf.z * s4.z + wf.w * s4.w;
            fd[n] += wf.x * d4.x + wf.y * d4.y + wf.z * d4.z + wf.w * d4.w;
        }
    }
    // ---- W part, K = 64 ----
    for (int k4 = 0; k4 < 16; ++k4) {
        float4 wi, wo, wu, wf;
        if constexpr (TR) {
            size_t base = (size_t)k4 * 1024 + tid;
            wi = WxT4[base];
            wo = WxT4[base + 256];
            wu = WxT4[base + 512];
            wf = WxT4[base + 768];
        } else {
            wi = *(const float4*)(Wiou + (size_t)tid * FIN + 4 * k4);
            wo = *(const float4*)(Wiou + (size_t)(tid + 256) * FIN + 4 * k4);
            wu = *(const float4*)(Wiou + (size_t)(tid + 512) * FIN + 4 * k4);
            float4 t3 = *(const float4*)(Wf + (size_t)tid * FIN + 4 * k4);
            wf.x = 2.0f * t3.x; wf.y = 2.0f * t3.y; wf.z = 2.0f * t3.z; wf.w = 2.0f * t3.w;
        }
#pragma unroll
        for (int n = 0; n < NB; ++n) {
            float4 x4 = ((const float4*)xs[n])[k4];
            ai[n] += wi.x * x4.x + wi.y * x4.y + wi.z * x4.z + wi.w * x4.w;
            ao[n] += wo.x * x4.x + wo.y * x4.y + wo.z * x4.z + wo.w * x4.w;
            au[n] += wu.x * x4.x + wu.y * x4.y + wu.z * x4.z + wu.w * x4.w;
            fs[n] += wf.x * x4.x + wf.y * x4.y + wf.z * x4.z + wf.w * x4.w;
        }
    }
}

// ---------------------------------------------------------------------------
// Leaves: iou = W_iou x + b; c = sig(i)*tanh(u); h = sig(o)*tanh(c).
// 16 leaves / block, 1024 blocks.
// ---------------------------------------------------------------------------
template<bool TR>
__global__ __launch_bounds__(256) void leaf_v2(
    const float* __restrict__ feat,
    const float* __restrict__ WxT, const float* __restrict__ Wiou,
    const float* __restrict__ biou,
    float* __restrict__ h, float* __restrict__ c)
{
    const int NB = 16;
    __shared__ float xs[NB][FIN];
    int tid = threadIdx.x;
    int l0 = blockIdx.x * NB;
    int b = l0 >> 7;
    int g0 = b * NPT + 127 + (l0 & 127);
    const float* fb = feat + (size_t)g0 * FIN;
    for (int i = tid; i < NB * FIN; i += 256) ((float*)xs)[i] = fb[i];
    __syncthreads();

    float ai[NB], ao[NB], au[NB];
#pragma unroll
    for (int n = 0; n < NB; ++n) { ai[n] = 0.f; ao[n] = 0.f; au[n] = 0.f; }

    const float4* WxT4 = (const float4*)WxT;
    for (int k4 = 0; k4 < 16; ++k4) {
        float4 wi, wo, wu;
        if constexpr (TR) {
            size_t base = (size_t)k4 * 1024 + tid;
            wi = WxT4[base]; wo = WxT4[base + 256]; wu = WxT4[base + 512];
        } else {
            wi = *(const float4*)(Wiou + (size_t)tid * FIN + 4 * k4);
            wo = *(const float4*)(Wiou + (size_t)(tid + 256) * FIN + 4 * k4);
            wu = *(const float4*)(Wiou + (size_t)(tid + 512) * FIN + 4 * k4);
        }
#pragma unroll
        for (int n = 0; n < NB; ++n) {
            float4 x4 = ((const float4*)xs[n])[k4];
            ai[n] += wi.x * x4.x + wi.y * x4.y + wi.z * x4.z + wi.w * x4.w;
            ao[n] += wo.x * x4.x + wo.y * x4.y + wo.z * x4.z + wo.w * x4.w;
            au[n] += wu.x * x4.x + wu.y * x4.y + wu.z * x4.z + wu.w * x4.w;
        }
    }

    float bi = biou[tid], bo = biou[tid + 256], bu = biou[tid + 512];
#pragma unroll
    for (int n = 0; n < NB; ++n) {
        float iv = sigf(ai[n] + bi);
        float ov = sigf(ao[n] + bo);
        float uv = tanh_fast(au[n] + bu);
        float cv = iv * uv;
        float hv = ov * tanh_fast(cv);
        c[(size_t)(g0 + n) * HH + tid] = cv;
        h[(size_t)(g0 + n) * HH + tid] = hv;
    }
}

// ---------------------------------------------------------------------------
// Internal levels t=1 (NB=16) and t=2 (NB=8).
// hs = h_c1 + h_c2, hd = h_c1 - h_c2; U_f h_ck = (fs +- fd)/2, with 2*W_f x
// folded into fs.
// ---------------------------------------------------------------------------
template<int NB, bool TR>
__global__ __launch_bounds__(256, 2) void internal_v2(
    const float* __restrict__ feat,
    const float* __restrict__ WT, const float* __restrict__ WxT,
    const float* __restrict__ Uiou, const float* __restrict__ Uf,
    const float* __restrict__ Wiou, const float* __restrict__ Wf,
    const float* __restrict__ biou, const float* __restrict__ bfv,
    float* __restrict__ h, float* __restrict__ c,
    int Lt, int lg)
{
    __shared__ float hs[NB][HH], hd[NB][HH];
    __shared__ float xs[NB][FIN];
    int tid = threadIdx.x;
    int m0 = blockIdx.x * NB;
    int b = m0 >> lg;
    int ii0 = Lt + (m0 & ((1 << lg) - 1));
    int g0 = b * NPT + ii0;
    int gc0 = g0 + ii0 + 1;              // = b*NPT + 2*ii0 + 1

#pragma unroll
    for (int j = 0; j < NB; ++j) {
        float a  = h[(size_t)(gc0 + 2 * j) * HH + tid];
        float bb = h[(size_t)(gc0 + 2 * j + 1) * HH + tid];
        hs[j][tid] = a + bb;
        hd[j][tid] = a - bb;
    }
    const float* fb = feat + (size_t)g0 * FIN;
    for (int i = tid; i < NB * FIN; i += 256) ((float*)xs)[i] = fb[i];
    __syncthreads();

    float ai[NB], ao[NB], au[NB], fs[NB], fd[NB];
#pragma unroll
    for (int n = 0; n < NB; ++n) { ai[n] = 0.f; ao[n] = 0.f; au[n] = 0.f; fs[n] = 0.f; fd[n] = 0.f; }

    dot_loops<NB, TR>(tid, WT, WxT, Uiou, Uf, Wiou, Wf, hs, hd, xs, ai, ao, au, fs, fd);

    float bi = biou[tid], bo = biou[tid + 256], bu = biou[tid + 512], bF = bfv[tid];
#pragma unroll
    for (int n = 0; n < NB; ++n) {
        float iv = sigf(ai[n] + bi);
        float ov = sigf(ao[n] + bo);
        float uv = tanh_fast(au[n] + bu);
        float f1 = sigf(0.5f * (fs[n] + fd[n]) + bF);
        float f2 = sigf(0.5f * (fs[n] - fd[n]) + bF);
        float c1 = c[(size_t)(gc0 + 2 * n) * HH + tid];
        float c2 = c[(size_t)(gc0 + 2 * n + 1) * HH + tid];
        float cv = iv * uv + f1 * c1 + f2 * c2;
        float hv = ov * tanh_fast(cv);
        c[(size_t)(g0 + n) * HH + tid] = cv;
        h[(size_t)(g0 + n) * HH + tid] = hv;
    }
}

// ---------------------------------------------------------------------------
// Merged tail, WIDE: one 1024-thread block per tree, levels nt=16,8,4,2,1.
// Thread (g = tid>>8, j = tid&255) owns output columns {j,+256,+512,+768}
// for node subset n == g (mod 4).
// __launch_bounds__(1024) — NO min-waves arg: a 1024-thread block needs 4
// waves/SIMD resident, so the implicit VGPR cap is 128. R3's (1024,4) made
// the compiler target 64 VGPRs -> inner-loop spills -> 430 MB scratch HBM
// traffic (FETCH 198 MB / WRITE 230 MB) and 479 us.
// ---------------------------------------------------------------------------
template<int NT, bool FIRST, bool TR>
__device__ void tw_level(
    int gb, const float* __restrict__ feat,
    const float* __restrict__ WT, const float* __restrict__ WxT,
    const float* __restrict__ Uiou, const float* __restrict__ Uf,
    const float* __restrict__ Wiou, const float* __restrict__ Wf,
    const float* __restrict__ biou, const float* __restrict__ bfv,
    float* __restrict__ h, float* __restrict__ c,
    float (*hl)[HH], float (*cl)[HH],
    float (*hs)[HH], float (*hd)[HH], float (*xs)[FIN])
{
    const int tid = threadIdx.x;
    const int j = tid & 255;
    const int g = tid >> 8;
    const int first = NT - 1;
    constexpr int NN = (NT >= 4) ? NT / 4 : 1;
    const bool act = (NT >= 4) || (g < NT);

    // build hs/hd (+stage x)
    if constexpr (FIRST) {
        for (int i = tid; i < NT * HH; i += 1024) {
            int n = i >> 8, k = i & 255;
            int ch = 2 * (first + n) + 1;
            float a  = h[(size_t)(gb + ch) * HH + k];
            float bb = h[(size_t)(gb + ch + 1) * HH + k];
            hs[n][k] = a + bb;
            hd[n][k] = a - bb;
        }
    } else {
        for (int i = tid; i < NT * HH; i += 1024) {
            int n = i >> 8, k = i & 255;
            int ch = 2 * (first + n) + 1;
            float a = hl[ch][k], bb = hl[ch + 1][k];
            hs[n][k] = a + bb;
            hd[n][k] = a - bb;
        }
    }
    for (int i = tid; i < NT * FIN; i += 1024)
        ((float*)xs)[i] = feat[(size_t)(gb + first) * FIN + i];
    __syncthreads();

    float ai[NN], ao[NN], au[NN], fs[NN], fd[NN];
#pragma unroll
    for (int q = 0; q < NN; ++q) { ai[q] = 0.f; ao[q] = 0.f; au[q] = 0.f; fs[q] = 0.f; fd[q] = 0.f; }

    if (act) {
        const float4* WT4  = (const float4*)WT;
        const float4* WxT4 = (const float4*)WxT;
        // ---- U part, K = 256 ----
        for (int k4 = 0; k4 < 64; ++k4) {
            float4 wi, wo, wu, wf;
            if constexpr (TR) {
                size_t base = (size_t)k4 * 1024 + j;
                wi = WT4[base];
                wo = WT4[base + 256];
                wu = WT4[base + 512];
                wf = WT4[base + 768];
            } else {
                wi = *(const float4*)(Uiou + (size_t)j * HH + 4 * k4);
                wo = *(const float4*)(Uiou + (size_t)(j + 256) * HH + 4 * k4);
                wu = *(const float4*)(Uiou + (size_t)(j + 512) * HH + 4 * k4);
                wf = *(const float4*)(Uf + (size_t)j * HH + 4 * k4);
            }
#pragma unroll
            for (int q = 0; q < NN; ++q) {
                int n = (NT >= 4) ? (g + 4 * q) : g;
                float4 s4 = ((const float4*)hs[n])[k4];
                float4 d4 = ((const float4*)hd[n])[k4];
                ai[q] += wi.x * s4.x + wi.y * s4.y + wi.z * s4.z + wi.w * s4.w;
                ao[q] += wo.x * s4.x + wo.y * s4.y + wo.z * s4.z + wo.w * s4.w;
                au[q] += wu.x * s4.x + wu.y * s4.y + wu.z * s4.z + wu.w * s4.w;
                fs[q] += wf.x * s4.x + wf.y * s4.y + wf.z * s4.z + wf.w * s4.w;
                fd[q] += wf.x * d4.x + wf.y * d4.y + wf.z * d4.z + wf.w * d4.w;
            }
        }
        // ---- W part, K = 64 ----
        for (int k4 = 0; k4 < 16; ++k4) {
            float4 wi, wo, wu, wf;
            if constexpr (TR) {
                size_t base = (size_t)k4 * 1024 + j;
                wi = WxT4[base];
                wo = WxT4[base + 256];
                wu = WxT4[base + 512];
                wf = WxT4[base + 768];
            } else {
                wi = *(const float4*)(Wiou + (size_t)j * FIN + 4 * k4);
                wo = *(const float4*)(Wiou + (size_t)(j + 256) * FIN + 4 * k4);
                wu = *(const float4*)(Wiou + (size_t)(j + 512) * FIN + 4 * k4);
                float4 t3 = *(const float4*)(Wf + (size_t)j * FIN + 4 * k4);
                wf.x = 2.0f * t3.x; wf.y = 2.0f * t3.y; wf.z = 2.0f * t3.z; wf.w = 2.0f * t3.w;
            }
#pragma unroll
            for (int q = 0; q < NN; ++q) {
                int n = (NT >= 4) ? (g + 4 * q) : g;
                float4 x4 = ((const float4*)xs[n])[k4];
                ai[q] += wi.x * x4.x + wi.y * x4.y + wi.z * x4.z + wi.w * x4.w;
                ao[q] += wo.x * x4.x + wo.y * x4.y + wo.z * x4.z + wo.w * x4.w;
                au[q] += wu.x * x4.x + wu.y * x4.y + wu.z * x4.z + wu.w * x4.w;
                fs[q] += wf.x * x4.x + wf.y * x4.y + wf.z * x4.z + wf.w * x4.w;
            }
        }

        float bi = biou[j], bo = biou[j + 256], bu = biou[j + 512], bF = bfv[j];
#pragma unroll
        for (int q = 0; q < NN; ++q) {
            int n = (NT >= 4) ? (g + 4 * q) : g;
            int node = first + n;
            int ch = 2 * node + 1;
            float iv = sigf(ai[q] + bi);
            float ov = sigf(ao[q] + bo);
            float uv = tanh_fast(au[q] + bu);
            float f1 = sigf(0.5f * (fs[q] + fd[q]) + bF);
            float f2 = sigf(0.5f * (fs[q] - fd[q]) + bF);
            float c1, c2;
            if constexpr (FIRST) {
                c1 = c[(size_t)(gb + ch) * HH + j];
                c2 = c[(size_t)(gb + ch + 1) * HH + j];
            } else {
                c1 = cl[ch][j];
                c2 = cl[ch + 1][j];
            }
            float cv = iv * uv + f1 * c1 + f2 * c2;
            float hv = ov * tanh_fast(cv);
            hl[node][j] = hv;
            cl[node][j] = cv;
            h[(size_t)(gb + node) * HH + j] = hv;
            c[(size_t)(gb + node) * HH + j] = cv;
        }
    }
    __syncthreads();   // protect hs/hd/hl/cl before next level
}

template<bool TR>
__global__ __launch_bounds__(1024) void tree_top_wide(
    const float* __restrict__ feat,
    const float* __restrict__ WT, const float* __restrict__ WxT,
    const float* __restrict__ Uiou, const float* __restrict__ Uf,
    const float* __restrict__ Wiou, const float* __restrict__ Wf,
    const float* __restrict__ biou, const float* __restrict__ bfv,
    float* __restrict__ h, float* __restrict__ c)
{
    __shared__ float hl[31][HH], cl[31][HH];
    __shared__ float hs[16][HH], hd[16][HH];
    __shared__ float xs[16][FIN];
    int gb = blockIdx.x * NPT;
    tw_level<16, true,  TR>(gb, feat, WT, WxT, Uiou, Uf, Wiou, Wf, biou, bfv, h, c, hl, cl, hs, hd, xs);
    tw_level<8,  false, TR>(gb, feat, WT, WxT, Uiou, Uf, Wiou, Wf, biou, bfv, h, c, hl, cl, hs, hd, xs);
    tw_level<4,  false, TR>(gb, feat, WT, WxT, Uiou, Uf, Wiou, Wf, biou, bfv, h, c, hl, cl, hs, hd, xs);
    tw_level<2,  false, TR>(gb, feat, WT, WxT, Uiou, Uf, Wiou, Wf, biou, bfv, h, c, hl, cl, hs, hd, xs);
    tw_level<1,  false, TR>(gb, feat, WT, WxT, Uiou, Uf, Wiou, Wf, biou, bfv, h, c, hl, cl, hs, hd, xs);
}

// ---------------------------------------------------------------------------
// Head, WIDE: 1024 threads/tree. g-groups split the 255-node mean 4-way and
// the lin0 K-reduction 4-way; final lin1 dot on g==0 waves.
// ---------------------------------------------------------------------------
__global__ __launch_bounds__(1024) void head_wide(
    const float* __restrict__ h,
    const float* __restrict__ l0w, const float* __restrict__ l0b,
    const float* __restrict__ l1w, const float* __restrict__ l1b,
    float* __restrict__ out)
{
    __shared__ float ms[4][HH];
    __shared__ float part[4][HH];
    __shared__ float red[4];
    int b = blockIdx.x, tid = threadIdx.x;
    int j = tid & 255, g = tid >> 8;
    const float* hb = h + (size_t)b * NPT * HH;

    float a = 0.f;
    for (int i = g; i < NPT; i += 4) a += hb[(size_t)i * HH + j];
    ms[g][j] = a;
    __syncthreads();
    if (g == 0) ms[0][j] = (ms[0][j] + ms[1][j] + ms[2][j] + ms[3][j]) * (1.0f / (float)NPT);
    __syncthreads();

    // lin0: thread (g,j) sums K-range [64g, 64(g+1)) of row j
    const float4* L0 = (const float4*)(l0w + (size_t)j * HH);
    float y = 0.f;
    for (int k4 = 16 * g; k4 < 16 * (g + 1); ++k4) {
        float4 w = L0[k4];
        float4 m4 = ((const float4*)ms[0])[k4];
        y += w.x * m4.x + w.y * m4.y + w.z * m4.z + w.w * m4.w;
    }
    part[g][j] = y;
    __syncthreads();

    if (g == 0) {
        float yy = part[0][j] + part[1][j] + part[2][j] + part[3][j] + l0b[j];
        yy = fmaxf(yy, 0.f);
        float v = yy * l1w[j];
        for (int off = 32; off > 0; off >>= 1) v += __shfl_down(v, off, 64);
        if ((j & 63) == 0) red[j >> 6] = v;
    }
    __syncthreads();
    if (tid == 0) out[b] = red[0] + red[1] + red[2] + red[3] + l1b[0];
}

// ---------------------------------------------------------------------------
extern "C" void kernel_launch(void* const* d_in, const int* in_sizes, int n_in,
                              void* d_out, int out_size, void* d_ws, size_t ws_size,
                              hipStream_t stream)
{
    const float* feat = (const float*)d_in[0];
    const float* Wiou = (const float*)d_in[4];
    const float* biou = (const float*)d_in[5];
    const float* Uiou = (const float*)d_in[6];
    const float* Wf   = (const float*)d_in[7];
    const float* bfv  = (const float*)d_in[8];
    const float* Uf   = (const float*)d_in[9];
    const float* l0w  = (const float*)d_in[10];
    const float* l0b  = (const float*)d_in[11];
    const float* l1w  = (const float*)d_in[12];
    const float* l1b  = (const float*)d_in[13];

    float* h  = (float*)d_ws;
    float* c  = h + (size_t)NTOT * HH;
    float* WT  = c + (size_t)NTOT * HH;
    float* WxT = WT + 256 * 1024;
    size_t need = ((size_t)NTOT * HH * 2 + 256 * 1024 + 64 * 1024) * sizeof(float);
    bool tr = (ws_size >= need);

    if (tr) {
        transpose_weights<<<1280, 256, 0, stream>>>(Uiou, Uf, Wiou, Wf, WT, WxT);
        leaf_v2<true><<<1024, 256, 0, stream>>>(feat, WxT, Wiou, biou, h, c);
        internal_v2<16, true><<<512, 256, 0, stream>>>(feat, WT, WxT, Uiou, Uf, Wiou, Wf,
                                                       biou, bfv, h, c, 63, 6);
        internal_v2<8, true><<<512, 256, 0, stream>>>(feat, WT, WxT, Uiou, Uf, Wiou, Wf,
                                                      biou, bfv, h, c, 31, 5);
        tree_top_wide<true><<<128, 1024, 0, stream>>>(feat, WT, WxT, Uiou, Uf, Wiou, Wf,
                                                      biou, bfv, h, c);
    } else {
        leaf_v2<false><<<1024, 256, 0, stream>>>(feat, WxT, Wiou, biou, h, c);
        internal_v2<16, false><<<512, 256, 0, stream>>>(feat, WT, WxT, Uiou, Uf, Wiou, Wf,
                                                        biou, bfv, h, c, 63, 6);
        internal_v2<8, false><<<512, 256, 0, stream>>>(feat, WT, WxT, Uiou, Uf, Wiou, Wf,
                                                       biou, bfv, h, c, 31, 5);
        tree_top_wide<false><<<128, 1024, 0, stream>>>(feat, WT, WxT, Uiou, Uf, Wiou, Wf,
                                                       biou, bfv, h, c);
    }
    head_wide<<<B_TREES, 1024, 0, stream>>>(h, l0w, l0b, l1w, l1b, (float*)d_out);
}